// Round 2
// baseline (1881.682 us; speedup 1.0000x reference)
//
#include <hip/hip_runtime.h>
#include <cstdint>

typedef unsigned short u16;
typedef unsigned int   u32;

// ---------- bf16 helpers ----------
__device__ __forceinline__ float bf2f(u16 b) { return __uint_as_float(((u32)b) << 16); }
__device__ __forceinline__ u16 f2bf(float f) {
    u32 u = __float_as_uint(f);
    u32 r = u + 0x7fffu + ((u >> 16) & 1u);   // round-to-nearest-even
    return (u16)(r >> 16);
}
__device__ __forceinline__ void unpack2(u32 u, float& a, float& b) {
    a = bf2f((u16)(u & 0xffffu)); b = bf2f((u16)(u >> 16));
}
// adaptive external read: fl=1 -> fp32 storage, fl=0 -> bf16 storage
__device__ __forceinline__ float ldx(const void* p, size_t i, int fl) {
    return fl ? ((const float*)p)[i] : bf2f(((const u16*)p)[i]);
}

typedef __bf16 bf16x8 __attribute__((ext_vector_type(8)));
typedef float  f32x4  __attribute__((ext_vector_type(4)));

__device__ __forceinline__ void gl16(const u16* g, u16* l) {
    __builtin_amdgcn_global_load_lds(
        (const __attribute__((address_space(1))) u32*)g,
        (__attribute__((address_space(3))) u32*)l, 16, 0, 0);
}

// ---------- dtype detector: bf16 weights have sane exponents; fp32-read-as-bf16 doesn't ----------
__global__ void detect_k(const u16* __restrict__ wq, int* __restrict__ flag) {
    if (threadIdx.x == 0 && blockIdx.x == 0) {
        int bad = 0;
        for (int i = 0; i < 256; i++) {
            float v = fabsf(bf2f(wq[i]));
            if (!(v == 0.f || (v > 1e-30f && v < 1e3f))) bad++;   // NaN also lands here
        }
        *flag = (bad >= 32) ? 1 : 0;
    }
}

// ---------- weight transpose+convert: src[R][C] (fp32 or bf16) -> dst[C][R] bf16 ----------
__global__ void transp_k(const void* __restrict__ s, u16* __restrict__ d, int R, int Cc,
                         const int* __restrict__ flag) {
    int fl = *flag;
    int e = blockIdx.x * 256 + threadIdx.x;
    if (e < R * Cc) {
        int r = e / Cc, c = e - r * Cc;
        d[(size_t)c * R + r] = fl ? f2bf(((const float*)s)[e]) : ((const u16*)s)[e];
    }
}

// ---------- rel-pos bias table: tab[h][i][j] = rel_table[rel_index[i*49+j]][h] ----------
__global__ void btab_k(const void* __restrict__ rel_table, const int* __restrict__ rel_index,
                       float* __restrict__ tab, const int* __restrict__ flag) {
    int fl = *flag;
    int e = blockIdx.x * 256 + threadIdx.x;
    if (e < 16 * 2401) {
        int h = e / 2401, ij = e - h * 2401;
        tab[e] = ldx(rel_table, (size_t)rel_index[ij] * 16 + h, fl);
    }
}

// ---------- LN1 + cyclic shift + window partition: x[B,784,512] -> win[50176,512] bf16 ----------
__global__ __launch_bounds__(256) void ln_win_k(const void* __restrict__ x,
        const void* __restrict__ g, const void* __restrict__ be, u16* __restrict__ win,
        const int* __restrict__ flag) {
    int fl = *flag;
    int lane = threadIdx.x & 63;
    int t = blockIdx.x * 4 + (threadIdx.x >> 6);
    int w = t / 49, p = t - w * 49;
    int bimg = w >> 4, nw = w & 15;
    int r = p / 7, c = p - r * 7;
    int hs = (nw >> 2) * 7 + r, wsx = (nw & 3) * 7 + c;
    int ho = hs + 3; if (ho >= 28) ho -= 28;
    int wo = wsx + 3; if (wo >= 28) wo -= 28;
    size_t base = ((size_t)bimg * 784 + (size_t)ho * 28 + wo) * 512 + lane * 8;
    float f[8];
    if (fl) {
        const float4* src = (const float4*)((const float*)x + base);
        float4 v0 = src[0], v1 = src[1];
        f[0]=v0.x; f[1]=v0.y; f[2]=v0.z; f[3]=v0.w; f[4]=v1.x; f[5]=v1.y; f[6]=v1.z; f[7]=v1.w;
    } else {
        uint4 u = *(const uint4*)((const u16*)x + base);
        unpack2(u.x, f[0], f[1]); unpack2(u.y, f[2], f[3]);
        unpack2(u.z, f[4], f[5]); unpack2(u.w, f[6], f[7]);
    }
    float s = 0.f, q = 0.f;
#pragma unroll
    for (int j = 0; j < 8; j++) { s += f[j]; q += f[j] * f[j]; }
#pragma unroll
    for (int o = 32; o; o >>= 1) { s += __shfl_xor(s, o, 64); q += __shfl_xor(q, o, 64); }
    float mean = s * (1.f / 512.f);
    float rstd = rsqrtf(q * (1.f / 512.f) - mean * mean + 1e-5f);
    u32 o[4];
#pragma unroll
    for (int j = 0; j < 4; j++) {
        float g0 = ldx(g, lane * 8 + 2 * j, fl),     b0 = ldx(be, lane * 8 + 2 * j, fl);
        float g1v = ldx(g, lane * 8 + 2 * j + 1, fl), b1v = ldx(be, lane * 8 + 2 * j + 1, fl);
        float y0 = (f[2 * j] - mean) * rstd * g0 + b0;
        float y1 = (f[2 * j + 1] - mean) * rstd * g1v + b1v;
        o[j] = (u32)f2bf(y0) | ((u32)f2bf(y1) << 16);
    }
    *(uint4*)(win + (size_t)t * 512 + lane * 8) = make_uint4(o[0], o[1], o[2], o[3]);
}

// ---------- LN2: x1 fp32 [50176,512] -> h2 bf16 ----------
__global__ __launch_bounds__(256) void ln2_k(const float* __restrict__ x1,
        const void* __restrict__ g, const void* __restrict__ be, u16* __restrict__ h2,
        const int* __restrict__ flag) {
    int fl = *flag;
    int lane = threadIdx.x & 63;
    int t = blockIdx.x * 4 + (threadIdx.x >> 6);
    const float4* src = (const float4*)(x1 + (size_t)t * 512 + lane * 8);
    float4 v0 = src[0], v1 = src[1];
    float f[8] = {v0.x, v0.y, v0.z, v0.w, v1.x, v1.y, v1.z, v1.w};
    float s = 0.f, q = 0.f;
#pragma unroll
    for (int j = 0; j < 8; j++) { s += f[j]; q += f[j] * f[j]; }
#pragma unroll
    for (int o = 32; o; o >>= 1) { s += __shfl_xor(s, o, 64); q += __shfl_xor(q, o, 64); }
    float mean = s * (1.f / 512.f);
    float rstd = rsqrtf(q * (1.f / 512.f) - mean * mean + 1e-5f);
    u32 o[4];
#pragma unroll
    for (int j = 0; j < 4; j++) {
        float g0 = ldx(g, lane * 8 + 2 * j, fl),     b0 = ldx(be, lane * 8 + 2 * j, fl);
        float g1v = ldx(g, lane * 8 + 2 * j + 1, fl), b1v = ldx(be, lane * 8 + 2 * j + 1, fl);
        float y0 = (f[2 * j] - mean) * rstd * g0 + b0;
        float y1 = (f[2 * j + 1] - mean) * rstd * g1v + b1v;
        o[j] = (u32)f2bf(y0) | ((u32)f2bf(y1) << 16);
    }
    *(uint4*)(h2 + (size_t)t * 512 + lane * 8) = make_uint4(o[0], o[1], o[2], o[3]);
}

// ---------- GEMM C = A[M,K] @ B (given as BT[N,K] bf16) + bias, epilogue by MODE ----------
// MODE 0: out bf16 [M,N] = (acc+bias)*alpha          (QKV; alpha folds 1/sqrt(HD) into q)
// MODE 1: x1 fp32 scatter: window-reverse+unshift, += x residual (adaptive dtype)
// MODE 2: out bf16 [M,N] = gelu_exact(acc+bias)      (MLP up)
// MODE 3: d_out (adaptive dtype) = acc+bias + x1 fp32 residual   (final output)
template <int MODE>
__global__ __launch_bounds__(256) void gemm_bt(
        const u16* __restrict__ A, const u16* __restrict__ BT, const void* __restrict__ bias,
        int M, int N, int K, float alpha,
        void* __restrict__ outv, float* __restrict__ outf,
        const void* __restrict__ resb, const float* __restrict__ resf, int m_off,
        const int* __restrict__ flag) {
    __shared__ __align__(16) u16 As[128 * 32];
    __shared__ __align__(16) u16 Bs[128 * 32];
    int fl = *flag;
    int tid = threadIdx.x;
    int wave = tid >> 6, lane = tid & 63;
    int l15 = lane & 15, quad = lane >> 4;
    int wm = (wave & 1) << 6, wn = (wave >> 1) << 6;
    int m0 = blockIdx.y * 128, n0 = blockIdx.x * 128;

    int srow0 = wave * 16 + (lane >> 2);
    int srow1 = srow0 + 64;
    int scol = (lane & 3) * 8;
    const u16* a0 = A + (size_t)(m0 + srow0) * K + scol;
    const u16* a1 = A + (size_t)(m0 + srow1) * K + scol;
    const u16* b0 = BT + (size_t)(n0 + srow0) * K + scol;
    const u16* b1 = BT + (size_t)(n0 + srow1) * K + scol;
    u16* lA0 = &As[wave * 16 * 32];
    u16* lA1 = &As[(wave + 4) * 16 * 32];
    u16* lB0 = &Bs[wave * 16 * 32];
    u16* lB1 = &Bs[(wave + 4) * 16 * 32];

    f32x4 acc[4][4];
#pragma unroll
    for (int mi = 0; mi < 4; mi++)
#pragma unroll
        for (int ni = 0; ni < 4; ni++) acc[mi][ni] = (f32x4){0.f, 0.f, 0.f, 0.f};

    for (int k0 = 0; k0 < K; k0 += 32) {
        gl16(a0, lA0); gl16(a1, lA1); gl16(b0, lB0); gl16(b1, lB1);
        a0 += 32; a1 += 32; b0 += 32; b1 += 32;
        __syncthreads();
        bf16x8 af[4], bfm[4];
#pragma unroll
        for (int mi = 0; mi < 4; mi++)
            af[mi] = *(const bf16x8*)&As[(wm + mi * 16 + l15) * 32 + quad * 8];
#pragma unroll
        for (int ni = 0; ni < 4; ni++)
            bfm[ni] = *(const bf16x8*)&Bs[(wn + ni * 16 + l15) * 32 + quad * 8];
#pragma unroll
        for (int mi = 0; mi < 4; mi++)
#pragma unroll
            for (int ni = 0; ni < 4; ni++)
                acc[mi][ni] = __builtin_amdgcn_mfma_f32_16x16x32_bf16(af[mi], bfm[ni], acc[mi][ni], 0, 0, 0);
        __syncthreads();
    }

#pragma unroll
    for (int mi = 0; mi < 4; mi++) {
#pragma unroll
        for (int r = 0; r < 4; r++) {
            int gm = m0 + wm + mi * 16 + quad * 4 + r;
            size_t obase = 0;
            if constexpr (MODE == 1) {
                int w = gm / 49, p = gm - w * 49;
                int bimg = w >> 4, nw = w & 15;
                int rr = p / 7, cc = p - rr * 7;
                int hs = (nw >> 2) * 7 + rr, wsx = (nw & 3) * 7 + cc;
                int ho = hs + 3; if (ho >= 28) ho -= 28;
                int wo2 = wsx + 3; if (wo2 >= 28) wo2 -= 28;
                obase = ((size_t)bimg * 784 + (size_t)ho * 28 + wo2) * 512;
            }
#pragma unroll
            for (int ni = 0; ni < 4; ni++) {
                int gn = n0 + wn + ni * 16 + l15;
                float v = acc[mi][ni][r] + ldx(bias, gn, fl);
                if constexpr (MODE == 0) {
                    ((u16*)outv)[(size_t)gm * N + gn] = f2bf(v * alpha);
                } else if constexpr (MODE == 1) {
                    size_t oi = obase + gn;
                    outf[oi] = v + ldx(resb, oi, fl);
                } else if constexpr (MODE == 2) {
                    ((u16*)outv)[(size_t)gm * N + gn] = f2bf(0.5f * v * (1.f + erff(v * 0.70710678118f)));
                } else {
                    size_t oi = (size_t)(m_off + gm) * 512 + gn;
                    float y = v + resf[oi];
                    if (fl) ((float*)outv)[oi] = y; else ((u16*)outv)[oi] = f2bf(y);
                }
            }
        }
    }
}

// ---------- windowed attention: one wave per (window, head) ----------
__global__ __launch_bounds__(64) void attn_k(const u16* __restrict__ qb,
        const u16* __restrict__ kb, const u16* __restrict__ vb,
        const float* __restrict__ tab, u16* __restrict__ ctx) {
    __shared__ float qs[49 * 33], ks[49 * 33], vs[49 * 33], sc[49 * 49];
    int bid = blockIdx.x;
    int w = bid >> 4, h = bid & 15;
    int nw = w & 15;
    int tid = threadIdx.x;
    size_t base = (size_t)w * 49 * 512 + h * 32;
    for (int e = tid; e < 1568; e += 64) {
        int i = e >> 5, d = e & 31;
        size_t gi = base + (size_t)i * 512 + d;
        qs[i * 33 + d] = bf2f(qb[gi]);
        ks[i * 33 + d] = bf2f(kb[gi]);
        vs[i * 33 + d] = bf2f(vb[gi]);
    }
    __syncthreads();
    int wy = (nw >> 2) * 7, wx = (nw & 3) * 7;
    for (int e = tid; e < 2401; e += 64) {
        int i = e / 49, j = e - i * 49;
        float s = 0.f;
#pragma unroll
        for (int d = 0; d < 32; d++) s += qs[i * 33 + d] * ks[j * 33 + d];
        int yi = wy + i / 7, xi = wx + i % 7;
        int yj = wy + j / 7, xj = wx + j % 7;
        int ri = (yi < 21 ? 0 : (yi < 25 ? 1 : 2)) * 3 + (xi < 21 ? 0 : (xi < 25 ? 1 : 2));
        int rj = (yj < 21 ? 0 : (yj < 25 ? 1 : 2)) * 3 + (xj < 21 ? 0 : (xj < 25 ? 1 : 2));
        float s2 = s + tab[h * 2401 + e];
        if (ri != rj) s2 -= 100.f;
        sc[e] = s2;
    }
    __syncthreads();
    if (tid < 49) {
        float mx = -1e30f;
#pragma unroll
        for (int j = 0; j < 49; j++) mx = fmaxf(mx, sc[tid * 49 + j]);
        float pr[49]; float sum = 0.f;
#pragma unroll
        for (int j = 0; j < 49; j++) { pr[j] = expf(sc[tid * 49 + j] - mx); sum += pr[j]; }
        float inv = 1.f / sum;
#pragma unroll
        for (int j = 0; j < 49; j++) sc[tid * 49 + j] = pr[j] * inv;
    }
    __syncthreads();
    for (int e = tid; e < 1568; e += 64) {
        int i = e >> 5, d = e & 31;
        float s = 0.f;
#pragma unroll
        for (int j = 0; j < 49; j++) s += sc[i * 49 + j] * vs[j * 33 + d];
        ctx[base + (size_t)i * 512 + d] = f2bf(s);
    }
}

extern "C" void kernel_launch(void* const* d_in, const int* in_sizes, int n_in,
                              void* d_out, int out_size, void* d_ws, size_t ws_size,
                              hipStream_t stream) {
    const void* x   = d_in[0];
    const void* g1  = d_in[1];
    const void* b1  = d_in[2];
    const void* wq  = d_in[3];
    const void* bq  = d_in[4];
    const void* wk  = d_in[5];
    const void* bk  = d_in[6];
    const void* wv  = d_in[7];
    const void* bv  = d_in[8];
    const void* rel_table = d_in[9];
    const void* wo  = d_in[10];
    const void* bo  = d_in[11];
    const void* g2  = d_in[12];
    const void* b2  = d_in[13];
    const void* wi  = d_in[14];
    const void* bi  = d_in[15];
    const void* wout = d_in[16];
    const void* bout = d_in[17];
    const int* rel_index = (const int*)d_in[18];

    char* ws = (char*)d_ws;
    const size_t SZ = (size_t)50176 * 512 * 2;   // one [50176,512] bf16 activation
    u16*   win = (u16*)(ws);                     // region0; later reused as ctx
    u16*   qb  = (u16*)(ws + SZ);                // region1
    u16*   kb  = (u16*)(ws + 2 * SZ);            // region2
    u16*   vb  = (u16*)(ws + 3 * SZ);            // region3; later reused as h2
    u16*   ctx = win;
    float* x1  = (float*)(ws + SZ);              // fp32, spans regions 1+2
    u16*   h2  = vb;
    u16*   mid = (u16*)(ws + 4 * SZ);            // [12544,2048] bf16 chunk == SZ bytes
    u16*   wt  = (u16*)(ws + 5 * SZ);
    u16*   wqT = wt;                             // 512x512 each
    u16*   wkT = wt + 262144;
    u16*   wvT = wt + 524288;
    u16*   woT = wt + 786432;
    u16*   wiT = wt + 1048576;                   // [2048,512]
    u16*   woutT = wt + 2097152;                 // [512,2048]
    float* tab = (float*)(ws + 5 * SZ + 6291456);
    int*   flag = (int*)(ws + 5 * SZ + 6291456 + 16 * 2401 * 4);

    // dtype detection (device-side, graph-capture safe)
    detect_k<<<1, 64, 0, stream>>>((const u16*)wq, flag);

    // weight transposes (convert to bf16) + bias table
    transp_k<<<1024, 256, 0, stream>>>(wq, wqT, 512, 512, flag);
    transp_k<<<1024, 256, 0, stream>>>(wk, wkT, 512, 512, flag);
    transp_k<<<1024, 256, 0, stream>>>(wv, wvT, 512, 512, flag);
    transp_k<<<1024, 256, 0, stream>>>(wo, woT, 512, 512, flag);
    transp_k<<<4096, 256, 0, stream>>>(wi, wiT, 512, 2048, flag);
    transp_k<<<4096, 256, 0, stream>>>(wout, woutT, 2048, 512, flag);
    btab_k<<<151, 256, 0, stream>>>(rel_table, rel_index, tab, flag);

    // LN1 + shift + window partition
    ln_win_k<<<12544, 256, 0, stream>>>(x, g1, b1, win, flag);

    // QKV projections (q pre-scaled by 1/sqrt(32))
    dim3 gq(4, 392);
    gemm_bt<0><<<gq, 256, 0, stream>>>(win, wqT, bq, 50176, 512, 512, 0.1767766953f,
                                       qb, nullptr, nullptr, nullptr, 0, flag);
    gemm_bt<0><<<gq, 256, 0, stream>>>(win, wkT, bk, 50176, 512, 512, 1.f,
                                       kb, nullptr, nullptr, nullptr, 0, flag);
    gemm_bt<0><<<gq, 256, 0, stream>>>(win, wvT, bv, 50176, 512, 512, 1.f,
                                       vb, nullptr, nullptr, nullptr, 0, flag);

    // windowed attention
    attn_k<<<16384, 64, 0, stream>>>(qb, kb, vb, tab, ctx);

    // output projection + window reverse + unshift + residual -> x1 (fp32)
    gemm_bt<1><<<gq, 256, 0, stream>>>(ctx, woT, bo, 50176, 512, 512, 1.f,
                                       nullptr, x1, x, nullptr, 0, flag);

    // LN2
    ln2_k<<<12544, 256, 0, stream>>>(x1, g2, b2, h2, flag);

    // MLP in 4 token-chunks of 12544 rows (mid buffer reuse)
    for (int c = 0; c < 4; c++) {
        dim3 g1m(16, 98), g2m(4, 98);
        gemm_bt<2><<<g1m, 256, 0, stream>>>(h2 + (size_t)c * 12544 * 512, wiT, bi,
                                            12544, 2048, 512, 1.f,
                                            mid, nullptr, nullptr, nullptr, 0, flag);
        gemm_bt<3><<<g2m, 256, 0, stream>>>(mid, woutT, bout,
                                            12544, 512, 2048, 1.f,
                                            d_out, nullptr, nullptr, x1, c * 12544, flag);
    }
}

// Round 3
// 1451.388 us; speedup vs baseline: 1.2965x; 1.2965x over previous
//
#include <hip/hip_runtime.h>
#include <cstdint>

typedef unsigned short u16;
typedef unsigned int   u32;

// ---------- bf16 helpers ----------
__device__ __forceinline__ float bf2f(u16 b) { return __uint_as_float(((u32)b) << 16); }
__device__ __forceinline__ u16 f2bf(float f) {
    u32 u = __float_as_uint(f);
    u32 r = u + 0x7fffu + ((u >> 16) & 1u);   // round-to-nearest-even
    return (u16)(r >> 16);
}
__device__ __forceinline__ void unpack2(u32 u, float& a, float& b) {
    a = bf2f((u16)(u & 0xffffu)); b = bf2f((u16)(u >> 16));
}
// adaptive external read: fl=1 -> fp32 storage, fl=0 -> bf16 storage
__device__ __forceinline__ float ldx(const void* p, size_t i, int fl) {
    return fl ? ((const float*)p)[i] : bf2f(((const u16*)p)[i]);
}

typedef __bf16 bf16x8 __attribute__((ext_vector_type(8)));
typedef float  f32x4  __attribute__((ext_vector_type(4)));

__device__ __forceinline__ void gl16(const u16* g, u16* l) {
    __builtin_amdgcn_global_load_lds(
        (const __attribute__((address_space(1))) u32*)g,
        (__attribute__((address_space(3))) u32*)l, 16, 0, 0);
}

// ---------- dtype detector: bf16 weights have sane exponents; fp32-read-as-bf16 doesn't ----------
__global__ void detect_k(const u16* __restrict__ wq, int* __restrict__ flag) {
    if (threadIdx.x == 0 && blockIdx.x == 0) {
        int bad = 0;
        for (int i = 0; i < 256; i++) {
            float v = fabsf(bf2f(wq[i]));
            if (!(v == 0.f || (v > 1e-30f && v < 1e3f))) bad++;   // NaN also lands here
        }
        *flag = (bad >= 32) ? 1 : 0;
    }
}

// ---------- weight transpose+convert: src[R][C] (fp32 or bf16) -> dst[C][R] bf16 ----------
__global__ void transp_k(const void* __restrict__ s, u16* __restrict__ d, int R, int Cc,
                         const int* __restrict__ flag) {
    int fl = *flag;
    int e = blockIdx.x * 256 + threadIdx.x;
    if (e < R * Cc) {
        int r = e / Cc, c = e - r * Cc;
        d[(size_t)c * R + r] = fl ? f2bf(((const float*)s)[e]) : ((const u16*)s)[e];
    }
}

// ---------- combined bias+mask table, fp32, layout tabm[nw*16+h][i][l15][ni] ----------
// value at (p,i,l,ni) corresponds to score col j = ni*16+l ; pads (i>=49 || j>=49) = -30000
__global__ void tabm_k(const void* __restrict__ rel_table, const int* __restrict__ rel_index,
                       float* __restrict__ tabm, const int* __restrict__ flag) {
    int fl = *flag;
    int e = blockIdx.x * 256 + threadIdx.x;    // 256 * 4096 = 1048576
    int p = e >> 12;
    int rem = e & 4095;
    int i = rem >> 6, l = (rem >> 2) & 15, ni = rem & 3;
    int j = ni * 16 + l;
    int nw = p >> 4, h = p & 15;
    float v = -30000.f;
    if (i < 49 && j < 49) {
        v = ldx(rel_table, (size_t)rel_index[i * 49 + j] * 16 + h, fl);
        int wy = (nw >> 2) * 7, wx = (nw & 3) * 7;
        int yi = wy + i / 7, xi = wx + i % 7;
        int yj = wy + j / 7, xj = wx + j % 7;
        int ri = (yi < 21 ? 0 : (yi < 25 ? 1 : 2)) * 3 + (xi < 21 ? 0 : (xi < 25 ? 1 : 2));
        int rj = (yj < 21 ? 0 : (yj < 25 ? 1 : 2)) * 3 + (xj < 21 ? 0 : (xj < 25 ? 1 : 2));
        if (ri != rj) v -= 100.f;
    }
    tabm[e] = v;
}

// ---------- LN1 + cyclic shift + window partition: x[B,784,512] -> win[50176,512] bf16 ----------
__global__ __launch_bounds__(256) void ln_win_k(const void* __restrict__ x,
        const void* __restrict__ g, const void* __restrict__ be, u16* __restrict__ win,
        const int* __restrict__ flag) {
    int fl = *flag;
    int lane = threadIdx.x & 63;
    int t = blockIdx.x * 4 + (threadIdx.x >> 6);
    int w = t / 49, p = t - w * 49;
    int bimg = w >> 4, nw = w & 15;
    int r = p / 7, c = p - r * 7;
    int hs = (nw >> 2) * 7 + r, wsx = (nw & 3) * 7 + c;
    int ho = hs + 3; if (ho >= 28) ho -= 28;
    int wo = wsx + 3; if (wo >= 28) wo -= 28;
    size_t base = ((size_t)bimg * 784 + (size_t)ho * 28 + wo) * 512 + lane * 8;
    float f[8];
    if (fl) {
        const float4* src = (const float4*)((const float*)x + base);
        float4 v0 = src[0], v1 = src[1];
        f[0]=v0.x; f[1]=v0.y; f[2]=v0.z; f[3]=v0.w; f[4]=v1.x; f[5]=v1.y; f[6]=v1.z; f[7]=v1.w;
    } else {
        uint4 u = *(const uint4*)((const u16*)x + base);
        unpack2(u.x, f[0], f[1]); unpack2(u.y, f[2], f[3]);
        unpack2(u.z, f[4], f[5]); unpack2(u.w, f[6], f[7]);
    }
    float s = 0.f, q = 0.f;
#pragma unroll
    for (int j = 0; j < 8; j++) { s += f[j]; q += f[j] * f[j]; }
#pragma unroll
    for (int o = 32; o; o >>= 1) { s += __shfl_xor(s, o, 64); q += __shfl_xor(q, o, 64); }
    float mean = s * (1.f / 512.f);
    float rstd = rsqrtf(q * (1.f / 512.f) - mean * mean + 1e-5f);
    u32 o[4];
#pragma unroll
    for (int j = 0; j < 4; j++) {
        float g0 = ldx(g, lane * 8 + 2 * j, fl),     b0 = ldx(be, lane * 8 + 2 * j, fl);
        float g1v = ldx(g, lane * 8 + 2 * j + 1, fl), b1v = ldx(be, lane * 8 + 2 * j + 1, fl);
        float y0 = (f[2 * j] - mean) * rstd * g0 + b0;
        float y1 = (f[2 * j + 1] - mean) * rstd * g1v + b1v;
        o[j] = (u32)f2bf(y0) | ((u32)f2bf(y1) << 16);
    }
    *(uint4*)(win + (size_t)t * 512 + lane * 8) = make_uint4(o[0], o[1], o[2], o[3]);
}

// ---------- LN2: x1 fp32 [50176,512] -> h2 bf16 ----------
__global__ __launch_bounds__(256) void ln2_k(const float* __restrict__ x1,
        const void* __restrict__ g, const void* __restrict__ be, u16* __restrict__ h2,
        const int* __restrict__ flag) {
    int fl = *flag;
    int lane = threadIdx.x & 63;
    int t = blockIdx.x * 4 + (threadIdx.x >> 6);
    const float4* src = (const float4*)(x1 + (size_t)t * 512 + lane * 8);
    float4 v0 = src[0], v1 = src[1];
    float f[8] = {v0.x, v0.y, v0.z, v0.w, v1.x, v1.y, v1.z, v1.w};
    float s = 0.f, q = 0.f;
#pragma unroll
    for (int j = 0; j < 8; j++) { s += f[j]; q += f[j] * f[j]; }
#pragma unroll
    for (int o = 32; o; o >>= 1) { s += __shfl_xor(s, o, 64); q += __shfl_xor(q, o, 64); }
    float mean = s * (1.f / 512.f);
    float rstd = rsqrtf(q * (1.f / 512.f) - mean * mean + 1e-5f);
    u32 o[4];
#pragma unroll
    for (int j = 0; j < 4; j++) {
        float g0 = ldx(g, lane * 8 + 2 * j, fl),     b0 = ldx(be, lane * 8 + 2 * j, fl);
        float g1v = ldx(g, lane * 8 + 2 * j + 1, fl), b1v = ldx(be, lane * 8 + 2 * j + 1, fl);
        float y0 = (f[2 * j] - mean) * rstd * g0 + b0;
        float y1 = (f[2 * j + 1] - mean) * rstd * g1v + b1v;
        o[j] = (u32)f2bf(y0) | ((u32)f2bf(y1) << 16);
    }
    *(uint4*)(h2 + (size_t)t * 512 + lane * 8) = make_uint4(o[0], o[1], o[2], o[3]);
}

// ---------- GEMM C = A[M,K] @ B (given as BT[N,K] bf16) + bias, epilogue by MODE ----------
template <int MODE>
__global__ __launch_bounds__(256) void gemm_bt(
        const u16* __restrict__ A, const u16* __restrict__ BT, const void* __restrict__ bias,
        int M, int N, int K, float alpha,
        void* __restrict__ outv, float* __restrict__ outf,
        const void* __restrict__ resb, const float* __restrict__ resf, int m_off,
        const int* __restrict__ flag) {
    __shared__ __align__(16) u16 As[128 * 32];
    __shared__ __align__(16) u16 Bs[128 * 32];
    int fl = *flag;
    int tid = threadIdx.x;
    int wave = tid >> 6, lane = tid & 63;
    int l15 = lane & 15, quad = lane >> 4;
    int wm = (wave & 1) << 6, wn = (wave >> 1) << 6;
    int m0 = blockIdx.y * 128, n0 = blockIdx.x * 128;

    int srow0 = wave * 16 + (lane >> 2);
    int srow1 = srow0 + 64;
    int scol = (lane & 3) * 8;
    const u16* a0 = A + (size_t)(m0 + srow0) * K + scol;
    const u16* a1 = A + (size_t)(m0 + srow1) * K + scol;
    const u16* b0 = BT + (size_t)(n0 + srow0) * K + scol;
    const u16* b1 = BT + (size_t)(n0 + srow1) * K + scol;
    u16* lA0 = &As[wave * 16 * 32];
    u16* lA1 = &As[(wave + 4) * 16 * 32];
    u16* lB0 = &Bs[wave * 16 * 32];
    u16* lB1 = &Bs[(wave + 4) * 16 * 32];

    f32x4 acc[4][4];
#pragma unroll
    for (int mi = 0; mi < 4; mi++)
#pragma unroll
        for (int ni = 0; ni < 4; ni++) acc[mi][ni] = (f32x4){0.f, 0.f, 0.f, 0.f};

    for (int k0 = 0; k0 < K; k0 += 32) {
        gl16(a0, lA0); gl16(a1, lA1); gl16(b0, lB0); gl16(b1, lB1);
        a0 += 32; a1 += 32; b0 += 32; b1 += 32;
        __syncthreads();
        bf16x8 af[4], bfm[4];
#pragma unroll
        for (int mi = 0; mi < 4; mi++)
            af[mi] = *(const bf16x8*)&As[(wm + mi * 16 + l15) * 32 + quad * 8];
#pragma unroll
        for (int ni = 0; ni < 4; ni++)
            bfm[ni] = *(const bf16x8*)&Bs[(wn + ni * 16 + l15) * 32 + quad * 8];
#pragma unroll
        for (int mi = 0; mi < 4; mi++)
#pragma unroll
            for (int ni = 0; ni < 4; ni++)
                acc[mi][ni] = __builtin_amdgcn_mfma_f32_16x16x32_bf16(af[mi], bfm[ni], acc[mi][ni], 0, 0, 0);
        __syncthreads();
    }

#pragma unroll
    for (int mi = 0; mi < 4; mi++) {
#pragma unroll
        for (int r = 0; r < 4; r++) {
            int gm = m0 + wm + mi * 16 + quad * 4 + r;
            size_t obase = 0;
            if constexpr (MODE == 1) {
                int w = gm / 49, p = gm - w * 49;
                int bimg = w >> 4, nw = w & 15;
                int rr = p / 7, cc = p - rr * 7;
                int hs = (nw >> 2) * 7 + rr, wsx = (nw & 3) * 7 + cc;
                int ho = hs + 3; if (ho >= 28) ho -= 28;
                int wo2 = wsx + 3; if (wo2 >= 28) wo2 -= 28;
                obase = ((size_t)bimg * 784 + (size_t)ho * 28 + wo2) * 512;
            }
#pragma unroll
            for (int ni = 0; ni < 4; ni++) {
                int gn = n0 + wn + ni * 16 + l15;
                float v = acc[mi][ni][r] + ldx(bias, gn, fl);
                if constexpr (MODE == 0) {
                    ((u16*)outv)[(size_t)gm * N + gn] = f2bf(v * alpha);
                } else if constexpr (MODE == 1) {
                    size_t oi = obase + gn;
                    outf[oi] = v + ldx(resb, oi, fl);
                } else if constexpr (MODE == 2) {
                    ((u16*)outv)[(size_t)gm * N + gn] = f2bf(0.5f * v * (1.f + erff(v * 0.70710678118f)));
                } else {
                    size_t oi = (size_t)(m_off + gm) * 512 + gn;
                    float y = v + resf[oi];
                    if (fl) ((float*)outv)[oi] = y; else ((u16*)outv)[oi] = f2bf(y);
                }
            }
        }
    }
}

// ---------- MFMA windowed attention: one wave per (window, head) ----------
// Ps: P matrix (C-layout -> A-layout round trip), stride 72 (+8 pad: 2-way conflicts only)
// Vs: V^T staged [d][j]
__global__ __launch_bounds__(64) void attn_mfma_k(const u16* __restrict__ qb,
        const u16* __restrict__ kb, const u16* __restrict__ vb,
        const float* __restrict__ tabm, u16* __restrict__ ctx) {
    __shared__ __align__(16) u16 Ps[64 * 72];
    __shared__ __align__(16) u16 Vs[32 * 72];
    int bid = blockIdx.x;
    int w = bid >> 4, h = bid & 15, nw = w & 15;
    int lane = threadIdx.x;
    int l15 = lane & 15, quad = lane >> 4;
    size_t base = (size_t)w * 49 * 512 + h * 32;

    // ---- stage V transposed: lane handles source row j=lane (clamped to 48) ----
    {
        int j = lane < 49 ? lane : 48;
        const u16* vr = vb + base + (size_t)j * 512;
        u16 vv[32];
        *(uint4*)&vv[0]  = *(const uint4*)(vr);
        *(uint4*)&vv[8]  = *(const uint4*)(vr + 8);
        *(uint4*)&vv[16] = *(const uint4*)(vr + 16);
        *(uint4*)&vv[24] = *(const uint4*)(vr + 24);
#pragma unroll
        for (int d = 0; d < 32; d++) Vs[d * 72 + lane] = vv[d];
    }

    // ---- QK^T via MFMA, fragments direct from global (rows clamped to 48) ----
    bf16x8 qf[4], kf[4];
#pragma unroll
    for (int t = 0; t < 4; t++) {
        int rq = t * 16 + l15; rq = rq < 49 ? rq : 48;
        qf[t] = *(const bf16x8*)(qb + base + (size_t)rq * 512 + quad * 8);
        kf[t] = *(const bf16x8*)(kb + base + (size_t)rq * 512 + quad * 8);
    }
    f32x4 acc[4][4];
#pragma unroll
    for (int mi = 0; mi < 4; mi++)
#pragma unroll
        for (int ni = 0; ni < 4; ni++) acc[mi][ni] = (f32x4){0.f, 0.f, 0.f, 0.f};
#pragma unroll
    for (int mi = 0; mi < 4; mi++)
#pragma unroll
        for (int ni = 0; ni < 4; ni++)
            acc[mi][ni] = __builtin_amdgcn_mfma_f32_16x16x32_bf16(qf[mi], kf[ni], acc[mi][ni], 0, 0, 0);

    // ---- add bias+mask table (pads = -30000), softmax in registers, P -> LDS bf16 ----
    const float* tb = tabm + (size_t)(nw * 16 + h) * 4096;
#pragma unroll
    for (int mi = 0; mi < 4; mi++) {
#pragma unroll
        for (int r = 0; r < 4; r++) {
            int i = mi * 16 + quad * 4 + r;
            float4 t = *(const float4*)(tb + i * 64 + l15 * 4);
            float s0 = acc[mi][0][r] + t.x;
            float s1 = acc[mi][1][r] + t.y;
            float s2 = acc[mi][2][r] + t.z;
            float s3 = acc[mi][3][r] + t.w;
            float mx = fmaxf(fmaxf(s0, s1), fmaxf(s2, s3));
#pragma unroll
            for (int o = 8; o; o >>= 1) mx = fmaxf(mx, __shfl_xor(mx, o, 64));
            float p0 = __expf(s0 - mx), p1 = __expf(s1 - mx);
            float p2 = __expf(s2 - mx), p3 = __expf(s3 - mx);
            float sum = p0 + p1 + p2 + p3;
#pragma unroll
            for (int o = 8; o; o >>= 1) sum += __shfl_xor(sum, o, 64);
            float inv = 1.f / sum;
            Ps[i * 72 +  0 + l15] = f2bf(p0 * inv);
            Ps[i * 72 + 16 + l15] = f2bf(p1 * inv);
            Ps[i * 72 + 32 + l15] = f2bf(p2 * inv);
            Ps[i * 72 + 48 + l15] = f2bf(p3 * inv);
        }
    }
    __syncthreads();

    // ---- PV via MFMA: A=P from Ps, B=V^T from Vs ----
    f32x4 oacc[4][2];
#pragma unroll
    for (int mi = 0; mi < 4; mi++)
#pragma unroll
        for (int ni = 0; ni < 2; ni++) oacc[mi][ni] = (f32x4){0.f, 0.f, 0.f, 0.f};
#pragma unroll
    for (int ks = 0; ks < 2; ks++) {
        bf16x8 pf[4], vf[2];
#pragma unroll
        for (int mi = 0; mi < 4; mi++)
            pf[mi] = *(const bf16x8*)&Ps[(mi * 16 + l15) * 72 + ks * 32 + quad * 8];
#pragma unroll
        for (int ni = 0; ni < 2; ni++)
            vf[ni] = *(const bf16x8*)&Vs[(ni * 16 + l15) * 72 + ks * 32 + quad * 8];
#pragma unroll
        for (int mi = 0; mi < 4; mi++)
#pragma unroll
            for (int ni = 0; ni < 2; ni++)
                oacc[mi][ni] = __builtin_amdgcn_mfma_f32_16x16x32_bf16(pf[mi], vf[ni], oacc[mi][ni], 0, 0, 0);
    }

    // ---- write ctx rows i<49 ----
#pragma unroll
    for (int mi = 0; mi < 4; mi++) {
#pragma unroll
        for (int r = 0; r < 4; r++) {
            int i = mi * 16 + quad * 4 + r;
            if (i < 49) {
                ctx[base + (size_t)i * 512 + l15]      = f2bf(oacc[mi][0][r]);
                ctx[base + (size_t)i * 512 + 16 + l15] = f2bf(oacc[mi][1][r]);
            }
        }
    }
}

extern "C" void kernel_launch(void* const* d_in, const int* in_sizes, int n_in,
                              void* d_out, int out_size, void* d_ws, size_t ws_size,
                              hipStream_t stream) {
    const void* x   = d_in[0];
    const void* g1  = d_in[1];
    const void* b1  = d_in[2];
    const void* wq  = d_in[3];
    const void* bq  = d_in[4];
    const void* wk  = d_in[5];
    const void* bk  = d_in[6];
    const void* wv  = d_in[7];
    const void* bv  = d_in[8];
    const void* rel_table = d_in[9];
    const void* wo  = d_in[10];
    const void* bo  = d_in[11];
    const void* g2  = d_in[12];
    const void* b2  = d_in[13];
    const void* wi  = d_in[14];
    const void* bi  = d_in[15];
    const void* wout = d_in[16];
    const void* bout = d_in[17];
    const int* rel_index = (const int*)d_in[18];

    char* ws = (char*)d_ws;
    const size_t SZ = (size_t)50176 * 512 * 2;   // one [50176,512] bf16 activation
    u16*   win = (u16*)(ws);                     // region0; later reused as ctx
    u16*   qb  = (u16*)(ws + SZ);                // region1
    u16*   kb  = (u16*)(ws + 2 * SZ);            // region2
    u16*   vb  = (u16*)(ws + 3 * SZ);            // region3; later reused as h2
    u16*   ctx = win;
    float* x1  = (float*)(ws + SZ);              // fp32, spans regions 1+2
    u16*   h2  = vb;
    u16*   mid = (u16*)(ws + 4 * SZ);            // [12544,2048] bf16 chunk == SZ bytes
    float* tabm = (float*)(ws + 4 * SZ);         // 4MB bias table: lives in mid before MLP
    u16*   wt  = (u16*)(ws + 5 * SZ);
    u16*   wqT = wt;                             // 512x512 each
    u16*   wkT = wt + 262144;
    u16*   wvT = wt + 524288;
    u16*   woT = wt + 786432;
    u16*   wiT = wt + 1048576;                   // [2048,512]
    u16*   woutT = wt + 2097152;                 // [512,2048]
    int*   flag = (int*)(ws + 5 * SZ + 6291456);

    // dtype detection (device-side, graph-capture safe)
    detect_k<<<1, 64, 0, stream>>>((const u16*)wq, flag);

    // weight transposes (convert to bf16) + combined bias+mask table (into mid region)
    transp_k<<<1024, 256, 0, stream>>>(wq, wqT, 512, 512, flag);
    transp_k<<<1024, 256, 0, stream>>>(wk, wkT, 512, 512, flag);
    transp_k<<<1024, 256, 0, stream>>>(wv, wvT, 512, 512, flag);
    transp_k<<<1024, 256, 0, stream>>>(wo, woT, 512, 512, flag);
    transp_k<<<4096, 256, 0, stream>>>(wi, wiT, 512, 2048, flag);
    transp_k<<<4096, 256, 0, stream>>>(wout, woutT, 2048, 512, flag);
    tabm_k<<<4096, 256, 0, stream>>>(rel_table, rel_index, tabm, flag);

    // LN1 + shift + window partition
    ln_win_k<<<12544, 256, 0, stream>>>(x, g1, b1, win, flag);

    // QKV projections (q pre-scaled by 1/sqrt(32))
    dim3 gq(4, 392);
    gemm_bt<0><<<gq, 256, 0, stream>>>(win, wqT, bq, 50176, 512, 512, 0.1767766953f,
                                       qb, nullptr, nullptr, nullptr, 0, flag);
    gemm_bt<0><<<gq, 256, 0, stream>>>(win, wkT, bk, 50176, 512, 512, 1.f,
                                       kb, nullptr, nullptr, nullptr, 0, flag);
    gemm_bt<0><<<gq, 256, 0, stream>>>(win, wvT, bv, 50176, 512, 512, 1.f,
                                       vb, nullptr, nullptr, nullptr, 0, flag);

    // MFMA windowed attention
    attn_mfma_k<<<16384, 64, 0, stream>>>(qb, kb, vb, tabm, ctx);

    // output projection + window reverse + unshift + residual -> x1 (fp32)
    gemm_bt<1><<<gq, 256, 0, stream>>>(ctx, woT, bo, 50176, 512, 512, 1.f,
                                       nullptr, x1, x, nullptr, 0, flag);

    // LN2
    ln2_k<<<12544, 256, 0, stream>>>(x1, g2, b2, h2, flag);

    // MLP in 4 token-chunks of 12544 rows (mid buffer reuse; tabm dead by now)
    for (int c = 0; c < 4; c++) {
        dim3 g1m(16, 98), g2m(4, 98);
        gemm_bt<2><<<g1m, 256, 0, stream>>>(h2 + (size_t)c * 12544 * 512, wiT, bi,
                                            12544, 2048, 512, 1.f,
                                            mid, nullptr, nullptr, nullptr, 0, flag);
        gemm_bt<3><<<g2m, 256, 0, stream>>>(mid, woutT, bout,
                                            12544, 512, 2048, 1.f,
                                            d_out, nullptr, nullptr, x1, c * 12544, flag);
    }
}